// Round 3
// baseline (177.139 us; speedup 1.0000x reference)
//
#include <hip/hip_runtime.h>

#define NBLOCK 64

// sin(x) for |x| <~ 200, abs error ~1e-7.
// Cody-Waite pi/2 reduction (2 fmas) + cephes polys on [-pi/4, pi/4].
__device__ __forceinline__ float fast_sinf(float x) {
    float kf = rintf(x * 0.63661977236758134f);   // round(x * 2/pi)
    int   q  = (int)kf;
    // pi/2 = HI + LO;  HI = float(pi/2), LO = pi/2 - HI = -4.3711390e-8
    float r = fmaf(kf, -1.5707963705062866f, x);  // x - k*HI (fma-exact product)
    r = fmaf(kf, 4.3711390001862171e-8f, r);      // - k*LO
    float z = r * r;
    // sin poly
    float s = fmaf(z, fmaf(z, -1.9515295891e-4f, 8.3321608736e-3f), -1.6666654611e-1f);
    float sinr = fmaf(z * r, s, r);
    // cos poly
    float c = fmaf(z, fmaf(z, 2.4433157118e-5f, -1.3887316255e-3f), 4.1666645683e-2f);
    float cosr = fmaf(z, fmaf(z, c, -0.5f), 1.0f);
    float res = (q & 1) ? cosr : sinr;
    return (q & 2) ? -res : res;
}

// Exact floored fmod vs float32(2*pi), bit-matching numpy fp32 semantics.
__device__ __forceinline__ float mod_two_pi(float x) {
    const float Y = 6.2831853071795864769f;       // rounds to float32 2*pi
    float kf = floorf(__fdiv_rn(x, Y));
    float m = fmaf(-kf, Y, x);
    if (m < 0.0f)  { kf -= 1.0f; m = fmaf(-kf, Y, x); }
    if (m >= Y)    { kf += 1.0f; m = fmaf(-kf, Y, x); }
    return m;
}

__global__ __launch_bounds__(256)
void fm_synth_kernel(const float* __restrict__ fm_params,
                     const float* __restrict__ f0_hz,
                     const float* __restrict__ phase_state,
                     float* __restrict__ out, int nv)
{
    // t-major sample buffer: addr(t, v) = t*256 + ((v + 4*(t>>2)) & 255).
    // Write side (fixed t, v = consecutive lanes): banks 2-way -> free.
    // Read side (store pass below): banks exactly 2-way -> free.
    // Exactly 64 KB -> 2 blocks/CU, 16 waves/CU; no per-thread sample array,
    // so no scratch spill (R1/R2 spilled smp[64] -> +134 MB of HBM writes).
    __shared__ float lds[NBLOCK * 256];

    int tid = threadIdx.x;
    int b   = blockIdx.x * 256 + tid;
    int bc  = min(b, nv - 1);          // clamped compute index
    bool live = (b < nv);

    // ---- loads -----------------------------------------------------------
    const float2* fm2 = (const float2*)fm_params;   // 6 floats/voice
    float2 p01 = fm2[bc * 3 + 0];
    float2 p23 = fm2[bc * 3 + 1];
    float2 p45 = fm2[bc * 3 + 2];
    float  f0  = fmaxf(f0_hz[bc], 1.0f);
    float4 st  = ((const float4*)phase_state)[bc];

    // ---- params — exact fp32 op order matching the reference -------------
    const float TWO_PI = 6.2831853071795864769f;
    float r1  = __fadd_rn(0.25f, __fmul_rn(p01.y, 15.75f));
    float fb1 = __fmul_rn(p23.x, 0.95f);
    float d2  = __fmul_rn(p23.y, 10.0f);
    float r2  = __fadd_rn(0.25f, __fmul_rn(p45.x, 15.75f));
    float fb2 = __fmul_rn(p45.y, 0.95f);
    float inc1 = __fdiv_rn(__fmul_rn(__fmul_rn(TWO_PI, f0), r1), 16000.0f);
    float inc2 = __fdiv_rn(__fmul_rn(__fmul_rn(TWO_PI, f0), r2), 16000.0f);

    float start1 = st.x, start2 = st.y;
    float l1 = st.z, l2 = st.w;

    // ---- 64-step feedback FM recurrence, samples streamed to LDS ---------
    float ss = 0.0f;
    int sw = tid;                      // swizzled column; updates every 4 t
#pragma unroll
    for (int t = 0; t < NBLOCK; ++t) {
        if ((t & 3) == 0) sw = (tid + t) & 255;   // 4*(t>>2) == t here
        float tf  = (float)t;
        float ph1 = tf * inc1 + start1;
        float ph2 = tf * inc2 + start2;
        float o1 = fast_sinf(ph1 + fb1 * l1);
        float o2 = fast_sinf(ph2 + d2 * o1 + fb2 * l2);
        l1 = o1;
        l2 = o2;
        lds[t * 256 + sw] = o2;        // ds_write_b32, no wait until barrier
        ss = fmaf(o2, o2, ss);
    }
    float inv = 1.0f / sqrtf(ss * 0.015625f + 1e-5f);   // 1/sqrt(mean + 1e-5)

    __syncthreads();

    // ---- store pass: fully coalesced 1 KB wave stores ---------------------
    // Lane L of wave w, iteration k: voice vv = 4k + (L>>4) (wave-local),
    // float4 index t4 = L&15. Global float4 addr = base + L -> contiguous.
    int lane = tid & 63;
    int w    = tid >> 6;
    int q    = lane >> 4;
    int t4   = lane & 15;
    float4* out4 = (float4*)out;
    int blockBase = blockIdx.x * 256;
#pragma unroll
    for (int k = 0; k < 16; ++k) {
        int vv = 4 * k + q;                        // voice within this wave
        float invk = __shfl(inv, vv, 64);          // computed by lane vv
        int v = w * 64 + vv;                       // voice within block
        int sw2 = (v + 4 * t4) & 255;              // matches write swizzle
        const float* src = &lds[(4 * t4) * 256 + sw2];
        float4 val;
        val.x = src[0]     * invk;
        val.y = src[256]   * invk;
        val.z = src[512]   * invk;
        val.w = src[768]   * invk;
        if (blockBase + v < nv)
            out4[(size_t)(blockBase + v) * 16 + t4] = val;
    }

    // ---- phase_end (coalesced: one float4 per thread) ---------------------
    float x1 = __fadd_rn(start1, __fmul_rn(64.0f, inc1));
    float x2 = __fadd_rn(start2, __fmul_rn(64.0f, inc2));
    float4 pe;
    pe.x = mod_two_pi(x1);
    pe.y = mod_two_pi(x2);
    pe.z = l1;
    pe.w = l2;
    if (live)
        ((float4*)(out + (size_t)nv * NBLOCK))[b] = pe;
}

extern "C" void kernel_launch(void* const* d_in, const int* in_sizes, int n_in,
                              void* d_out, int out_size, void* d_ws, size_t ws_size,
                              hipStream_t stream) {
    const float* fm_params   = (const float*)d_in[0];
    const float* f0_hz       = (const float*)d_in[1];
    const float* phase_state = (const float*)d_in[2];
    float* out = (float*)d_out;
    int nv = in_sizes[1];                      // f0_hz has one element per voice
    int grid = (nv + 255) / 256;
    fm_synth_kernel<<<grid, 256, 0, stream>>>(fm_params, f0_hz, phase_state, out, nv);
}

// Round 4
// 176.637 us; speedup vs baseline: 1.0028x; 1.0028x over previous
//
#include <hip/hip_runtime.h>

#define NBLOCK 64

// sin(x) for |x| <~ 200, abs error ~1e-7.
// Cody-Waite pi/2 reduction (2 fmas) + cephes polys on [-pi/4, pi/4].
__device__ __forceinline__ float fast_sinf(float x) {
    float kf = rintf(x * 0.63661977236758134f);   // round(x * 2/pi)
    int   q  = (int)kf;
    // pi/2 = HI + LO;  HI = float(pi/2), LO = pi/2 - HI = -4.3711390e-8
    float r = fmaf(kf, -1.5707963705062866f, x);  // x - k*HI (fma-exact product)
    r = fmaf(kf, 4.3711390001862171e-8f, r);      // - k*LO
    float z = r * r;
    // sin poly
    float s = fmaf(z, fmaf(z, -1.9515295891e-4f, 8.3321608736e-3f), -1.6666654611e-1f);
    float sinr = fmaf(z * r, s, r);
    // cos poly
    float c = fmaf(z, fmaf(z, 2.4433157118e-5f, -1.3887316255e-3f), 4.1666645683e-2f);
    float cosr = fmaf(z, fmaf(z, c, -0.5f), 1.0f);
    float res = (q & 1) ? cosr : sinr;
    return (q & 2) ? -res : res;
}

// Exact floored fmod vs float32(2*pi), bit-matching numpy fp32 semantics.
__device__ __forceinline__ float mod_two_pi(float x) {
    const float Y = 6.2831853071795864769f;       // rounds to float32 2*pi
    float kf = floorf(__fdiv_rn(x, Y));
    float m = fmaf(-kf, Y, x);
    if (m < 0.0f)  { kf -= 1.0f; m = fmaf(-kf, Y, x); }
    if (m >= Y)    { kf += 1.0f; m = fmaf(-kf, Y, x); }
    return m;
}

// One wave per 64-thread block; wave-local 16 KB LDS transpose buffer.
// Rolled recurrence loop (16 x 4-unrolled) keeps the hot loop ~1.5 KB so it
// is I$-resident — the fully-unrolled variants (R0..R3) streamed ~22 KB of
// straight-line code per wave and sat ~75% fetch-stalled (VALUBusy 25%).
__global__ __launch_bounds__(64)
void fm_synth_kernel(const float* __restrict__ fm_params,
                     const float* __restrict__ f0_hz,
                     const float* __restrict__ phase_state,
                     float* __restrict__ out, int nv)
{
    // [t][col] with col = (lane + (t & ~3)) & 63.
    // Write banks: lanes 0..63 at fixed t -> 2-way (free, m136).
    // Read banks (store pass): q + 4*t4 spans 0..63 -> 2-way (free).
    __shared__ float lds[NBLOCK * 64];   // 16 KB -> 10 blocks/CU

    int lane = threadIdx.x;              // block == one wave
    int b    = blockIdx.x * 64 + lane;
    int bc   = min(b, nv - 1);           // clamped compute index
    bool live = (b < nv);

    // ---- loads -----------------------------------------------------------
    const float2* fm2 = (const float2*)fm_params;   // 6 floats/voice
    float2 p01 = fm2[bc * 3 + 0];
    float2 p23 = fm2[bc * 3 + 1];
    float2 p45 = fm2[bc * 3 + 2];
    float  f0  = fmaxf(f0_hz[bc], 1.0f);
    float4 st  = ((const float4*)phase_state)[bc];

    // ---- params — exact fp32 op order matching the reference -------------
    const float TWO_PI = 6.2831853071795864769f;
    float r1  = __fadd_rn(0.25f, __fmul_rn(p01.y, 15.75f));
    float fb1 = __fmul_rn(p23.x, 0.95f);
    float d2  = __fmul_rn(p23.y, 10.0f);
    float r2  = __fadd_rn(0.25f, __fmul_rn(p45.x, 15.75f));
    float fb2 = __fmul_rn(p45.y, 0.95f);
    float inc1 = __fdiv_rn(__fmul_rn(__fmul_rn(TWO_PI, f0), r1), 16000.0f);
    float inc2 = __fdiv_rn(__fmul_rn(__fmul_rn(TWO_PI, f0), r2), 16000.0f);

    float start1 = st.x, start2 = st.y;
    float l1 = st.z, l2 = st.w;

    // ---- 64-step feedback FM recurrence, rolled 16 x 4 -------------------
    float ss = 0.0f;
#pragma unroll 1
    for (int j = 0; j < 16; ++j) {
        int sw = (lane + 4 * j) & 63;
        float* row = &lds[4 * j * 64 + sw];
        float tj = (float)(4 * j);
#pragma unroll
        for (int c = 0; c < 4; ++c) {
            float tf  = tj + (float)c;              // exact (small ints)
            float ph1 = fmaf(tf, inc1, start1);
            float ph2 = fmaf(tf, inc2, start2);
            float o1 = fast_sinf(fmaf(fb1, l1, ph1));
            float o2 = fast_sinf(fmaf(fb2, l2, fmaf(d2, o1, ph2)));
            l1 = o1;
            l2 = o2;
            row[c * 64] = o2;                        // ds_write_b32
            ss = fmaf(o2, o2, ss);
        }
    }
    float inv = 1.0f / sqrtf(ss * 0.015625f + 1e-5f);   // 1/sqrt(mean + 1e-5)

    __syncthreads();   // single-wave workgroup: cheap; orders LDS write->read

    // ---- store pass: contiguous 1 KB wave stores --------------------------
    // Lane L = 16q + t4: voice vv = 4k + q, float4 index t4. Per k, the 64
    // lanes cover voices 4k..4k+3 x 16 float4s = 1 KB contiguous.
    int q  = lane >> 4;
    int t4 = lane & 15;
    float4* out4 = (float4*)out;
    int blockBase = blockIdx.x * 64;
    const float* srcRow = &lds[4 * t4 * 64];
#pragma unroll 4
    for (int k = 0; k < 16; ++k) {
        int vv = 4 * k + q;
        float invk = __shfl(inv, vv, 64);            // lane vv computed it
        const float* s = srcRow + ((vv + 4 * t4) & 63);
        float4 val;
        val.x = s[0]   * invk;
        val.y = s[64]  * invk;
        val.z = s[128] * invk;
        val.w = s[192] * invk;
        if (blockBase + vv < nv)
            out4[(size_t)(blockBase + vv) * 16 + t4] = val;
    }

    // ---- phase_end (coalesced: one float4 per thread) ---------------------
    float x1 = __fadd_rn(start1, __fmul_rn(64.0f, inc1));
    float x2 = __fadd_rn(start2, __fmul_rn(64.0f, inc2));
    float4 pe;
    pe.x = mod_two_pi(x1);
    pe.y = mod_two_pi(x2);
    pe.z = l1;
    pe.w = l2;
    if (live)
        ((float4*)(out + (size_t)nv * NBLOCK))[b] = pe;
}

extern "C" void kernel_launch(void* const* d_in, const int* in_sizes, int n_in,
                              void* d_out, int out_size, void* d_ws, size_t ws_size,
                              hipStream_t stream) {
    const float* fm_params   = (const float*)d_in[0];
    const float* f0_hz       = (const float*)d_in[1];
    const float* phase_state = (const float*)d_in[2];
    float* out = (float*)d_out;
    int nv = in_sizes[1];                      // f0_hz has one element per voice
    int grid = (nv + 63) / 64;
    fm_synth_kernel<<<grid, 64, 0, stream>>>(fm_params, f0_hz, phase_state, out, nv);
}